// Round 8
// baseline (578.155 us; speedup 1.0000x reference)
//
#include <hip/hip_runtime.h>
#include <hip/hip_bf16.h>

#define C3 768
#define PIX 4096
#define NB 8

typedef __attribute__((ext_vector_type(8))) short bf16x8;
typedef __attribute__((ext_vector_type(4))) float f32x4;

__device__ __forceinline__ unsigned short f2bf(float f) {
    unsigned int u = __float_as_uint(f);
    u += 0x7fffu + ((u >> 16) & 1u);          // round-to-nearest-even
    return (unsigned short)(u >> 16);
}
__device__ __forceinline__ float bf2f(unsigned short h) {
    return __uint_as_float((unsigned int)h << 16);
}

// Direct global->LDS DMA, 16B per lane; LDS dest = wave-uniform base + lane*16.
__device__ __forceinline__ void gload_lds16(const void* g, void* l) {
    __builtin_amdgcn_global_load_lds(
        (const __attribute__((address_space(1))) void*)g,
        (__attribute__((address_space(3))) void*)l, 16, 0, 0);
}

// ---------------------------------------------------------------------------
// 3-way split of fp32 into bf16 s0+s1+s2 (residual ~2^-27).
// ---------------------------------------------------------------------------
__global__ __launch_bounds__(256) void split3_kernel(
    const float* __restrict__ src, unsigned short* __restrict__ d,
    size_t stride, int n)
{
    int i = blockIdx.x * 256 + threadIdx.x;
    if (i < n) {
        float f = src[i];
        unsigned short h0 = f2bf(f);  float r1 = f - bf2f(h0);
        unsigned short h1 = f2bf(r1); float r2 = r1 - bf2f(h1);
        d[i]              = h0;
        d[i + stride]     = h1;
        d[i + 2 * stride] = f2bf(r2);
    }
}

// 2-way split (residual ~2^-18) — for proj weights.
__global__ __launch_bounds__(256) void split2_kernel(
    const float* __restrict__ src, unsigned short* __restrict__ d,
    size_t stride, int n)
{
    int i = blockIdx.x * 256 + threadIdx.x;
    if (i < n) {
        float f = src[i];
        unsigned short h0 = f2bf(f);
        d[i]          = h0;
        d[i + stride] = f2bf(f - bf2f(h0));
    }
}

// ---------------------------------------------------------------------------
// Transpose-convert: x[b][k=256][p=4096] -> xT [3 splits][b*PIX+p][k] bf16.
// ---------------------------------------------------------------------------
__global__ __launch_bounds__(256) void transpose_split3_kernel(
    const float* __restrict__ src, unsigned short* __restrict__ d, size_t stride)
{
    __shared__ float t[32][33];
    const int b  = blockIdx.z;
    const int p0 = blockIdx.x * 32;
    const int k0 = blockIdx.y * 32;
    const int tx = threadIdx.x & 31, ty = threadIdx.x >> 5;   // 32 x 8

    const float* s = src + ((size_t)b * 256 + k0) * PIX + p0;
#pragma unroll
    for (int i = 0; i < 4; ++i)
        t[ty + i * 8][tx] = s[(size_t)(ty + i * 8) * PIX + tx];   // t[k][p]
    __syncthreads();
#pragma unroll
    for (int i = 0; i < 4; ++i) {
        const int p = ty + i * 8;
        float f = t[tx][p];                   // (k=k0+tx, p=p0+p)
        unsigned short h0 = f2bf(f);  float r1 = f - bf2f(h0);
        unsigned short h1 = f2bf(r1); float r2 = r1 - bf2f(h1);
        size_t o = ((size_t)b * PIX + p0 + p) * 256 + k0 + tx;
        d[o]              = h0;
        d[o + stride]     = h1;
        d[o + 2 * stride] = f2bf(r2);
    }
}

// ---------------------------------------------------------------------------
// Split-bf16 MFMA GEMM, S splits, products with i+j < S.
//   Y[b,m,p] = sum_k W[m,k] * B[(b,p)][k] + bias[m]
// BM=128, BN=64, BK=64. 4 waves, each 64x32 (4x2 mfma_16x16x32 subtiles).
// Staging via global_load_lds; swizzle via pre-swizzled global source.
// XCD-chunked blockIdx swizzle for per-XCD L2 reuse.
// ---------------------------------------------------------------------------
template <int K, int S>
__global__ __launch_bounds__(256) void gemm_mfma_splitS(
    const unsigned short* __restrict__ A, const unsigned short* __restrict__ Bm,
    const float* __restrict__ bias, float* __restrict__ Y,
    int Mtiles, int M, size_t strideA, size_t strideB)
{
    __shared__ char lds[S * 24576];
    char* sA[S];
    char* sB[S];
#pragma unroll
    for (int s = 0; s < S; ++s) {
        sA[s] = lds + s * 16384;                 // 128 rows x 128B
        sB[s] = lds + S * 16384 + s * 8192;      // 64 rows x 128B
    }

    // XCD-chunked swizzle (gridDim.x is always a multiple of 8 here)
    const int nwg = gridDim.x;
    const int per = nwg >> 3;
    const int bid = blockIdx.x;
    const int wg  = (bid & 7) * per + (bid >> 3);
    const int tm  = wg % Mtiles;
    const int tn  = wg / Mtiles;
    const int bm  = tm * 128;
    const int gn0 = tn * 64;                     // global B-row = b*4096+p

    const int tid  = threadIdx.x;
    const int lane = tid & 63;
    const int wv   = tid >> 6;
    const int m0w  = (wv & 1) * 64;
    const int n0w  = (wv >> 1) * 32;

    // staging: wave wv deposits 1024B = 8 rows x 128B; lane l -> row rowbase+(l>>3),
    // global chunk = (l&7)*16 ^ ((l>>3)<<4)  (row&7 == l>>3).
    const int l8  = lane >> 3;
    const int c16 = (lane & 7) * 16;
    const int gchunk = (c16 ^ (l8 << 4)) >> 1;          // elements
    const unsigned short* gA = A  + (size_t)(bm  + wv * 8 + l8) * K + gchunk;
    const unsigned short* gB = Bm + (size_t)(gn0 + wv * 8 + l8) * K + gchunk;
    const int ldsw = wv * 1024;

    f32x4 acc[4][2] = {};

    for (int k0 = 0; k0 < K; k0 += 64) {
        __syncthreads();                 // previous compute done before overwrite
#pragma unroll
        for (int s = 0; s < S; ++s) {
#pragma unroll
            for (int j = 0; j < 4; ++j)  // A: 128 rows = 4 calls x (4 waves x 8 rows)
                gload_lds16(gA + s * strideA + (size_t)j * 32 * K + k0,
                            sA[s] + ldsw + j * 4096);
#pragma unroll
            for (int j = 0; j < 2; ++j)  // B: 64 rows
                gload_lds16(gB + s * strideB + (size_t)j * 32 * K + k0,
                            sB[s] + ldsw + j * 4096);
        }
        __syncthreads();                 // compiler drains vmcnt(0) before barrier

#pragma unroll
        for (int kk = 0; kk < 2; ++kk) {
            const int kbyte = (kk * 32 + (lane >> 4) * 8) * 2;
            bf16x8 bfr[S][2];
#pragma unroll
            for (int ni = 0; ni < 2; ++ni) {
                const int r = n0w + ni * 16 + (lane & 15);
                const int byte = r * 128 + (kbyte ^ ((r & 7) << 4));
#pragma unroll
                for (int s = 0; s < S; ++s)
                    bfr[s][ni] = *(const bf16x8*)(sB[s] + byte);
            }
#pragma unroll
            for (int mi = 0; mi < 4; ++mi) {
                bf16x8 afr[S];
                const int r = m0w + mi * 16 + (lane & 15);
                const int byte = r * 128 + (kbyte ^ ((r & 7) << 4));
#pragma unroll
                for (int s = 0; s < S; ++s)
                    afr[s] = *(const bf16x8*)(sA[s] + byte);
#pragma unroll
                for (int ni = 0; ni < 2; ++ni) {
#pragma unroll
                    for (int i = 0; i < S; ++i)
#pragma unroll
                        for (int j = 0; j < S; ++j)
                            if (i + j < S)
                                acc[mi][ni] = __builtin_amdgcn_mfma_f32_16x16x32_bf16(
                                    afr[i], bfr[j][ni], acc[mi][ni], 0, 0, 0);
                }
            }
        }
    }

    const int b  = gn0 >> 12;
    const int p0 = gn0 & 4095;
#pragma unroll
    for (int mi = 0; mi < 4; ++mi)
#pragma unroll
        for (int ni = 0; ni < 2; ++ni) {
            const int p = p0 + n0w + ni * 16 + (lane & 15);
#pragma unroll
            for (int i = 0; i < 4; ++i) {
                const int m = bm + m0w + mi * 16 + (lane >> 4) * 4 + i;
                Y[((size_t)b * M + m) * PIX + p] = acc[mi][ni][i] + bias[m];
            }
        }
}

// ---------------------------------------------------------------------------
// Fused depthwise(3x3 & 5x5) + grouped pointwise (24->24), one group/block.
// v2: LDS-staged zero-padded 8x68 tile per channel (double-buffered, 1 sync
// per channel); pw accumulated as outer product in registers -> no d3/d5 LDS.
// ---------------------------------------------------------------------------
__global__ __launch_bounds__(256) void dwpw_kernel(
    const float* __restrict__ qkv,
    const float* __restrict__ w3,  const float* __restrict__ b3,
    const float* __restrict__ w5,  const float* __restrict__ b5,
    const float* __restrict__ pw3w, const float* __restrict__ pw3b,
    const float* __restrict__ pw5w, const float* __restrict__ pw5b,
    float* __restrict__ t3, float* __restrict__ t5)
{
    __shared__ float tile[2][8][68];        // 4352 B total

    const int g   = blockIdx.y;
    const int b   = blockIdx.z;
    const int tid = threadIdx.x;
    const int p   = blockIdx.x * 256 + tid; // output pixel
    const int r0  = blockIdx.x * 4;         // first output row of this block
    const int c0  = g * 24;
    const int lr  = tid >> 6;               // local row 0..3
    const int lc  = tid & 63;               // col 0..63

    const float* src0 = qkv + ((size_t)b * C3 + c0) * PIX;

    // register accumulators for the grouped pointwise (outer-product form)
    float o3[24], o5[24];
#pragma unroll
    for (int co = 0; co < 24; ++co) {
        o3[co] = pw3b[c0 + co];
        o5[co] = pw5b[c0 + co];
    }

    // stage channel ic into buffer buf (zero-padded 8x68 halo tile)
    auto stage = [&](int ic, int buf) {
        const float* src = src0 + (size_t)ic * PIX;
#pragma unroll
        for (int e = tid; e < 544; e += 256) {
            const int rr = e / 68, cc = e % 68;
            const int gr = r0 - 2 + rr, gc = cc - 2;
            float v = 0.f;
            if ((unsigned)gr < 64u && (unsigned)gc < 64u) v = src[gr * 64 + gc];
            tile[buf][rr][cc] = v;
        }
    };

    stage(0, 0);
    for (int ic = 0; ic < 24; ++ic) {
        __syncthreads();                    // stage(ic) visible; compute(ic-1) done
        if (ic + 1 < 24) stage(ic + 1, (ic + 1) & 1);

        const int c = c0 + ic;
        const float* k5 = w5 + c * 25;
        const float* k3 = w3 + c * 9;
        const float (*T)[68] = tile[ic & 1];

        float acc3 = b3[c], acc5 = b5[c];
#pragma unroll
        for (int dy = 0; dy < 5; ++dy) {
#pragma unroll
            for (int dx = 0; dx < 5; ++dx) {
                const float v = T[lr + dy][lc + dx];
                acc5 = fmaf(k5[dy * 5 + dx], v, acc5);
                if (dy >= 1 && dy <= 3 && dx >= 1 && dx <= 3)
                    acc3 = fmaf(k3[(dy - 1) * 3 + (dx - 1)], v, acc3);
            }
        }

        const float* w3g = pw3w + (size_t)c0 * 24 + ic;   // pw3w[(c0+co)*24+ic]
        const float* w5g = pw5w + (size_t)c0 * 24 + ic;
#pragma unroll
        for (int co = 0; co < 24; ++co) {
            o3[co] = fmaf(w3g[co * 24], acc3, o3[co]);
            o5[co] = fmaf(w5g[co * 24], acc5, o5[co]);
        }
    }

    float* dst3 = t3 + ((size_t)b * C3 + c0) * PIX + p;
    float* dst5 = t5 + ((size_t)b * C3 + c0) * PIX + p;
#pragma unroll
    for (int co = 0; co < 24; ++co) {
        dst3[(size_t)co * PIX] = o3[co];
        dst5[(size_t)co * PIX] = o5[co];
    }
}

// ---------------------------------------------------------------------------
// vk[b,hh][d(9)][e(8)] = sum_p v_aug[d,p] * relu(k[e,p])
// ---------------------------------------------------------------------------
__global__ __launch_bounds__(256) void vk_reduce_kernel(
    const float* __restrict__ qkv, const float* __restrict__ s3,
    const float* __restrict__ s5, float* __restrict__ vkout)
{
    const int hh = blockIdx.x;  // 0..95
    const int b  = blockIdx.y;
    const float* src = (hh < 32) ? qkv : ((hh < 64) ? s3 : s5);
    const int ch0 = (hh & 31) * 24;
    const float* base = src + ((size_t)b * C3 + ch0) * PIX;

    float acc[9][8] = {};
    for (int p = threadIdx.x; p < PIX; p += 256) {
        float kk[8], vv[8];
#pragma unroll
        for (int e = 0; e < 8; ++e) kk[e] = fmaxf(base[(8 + e) * PIX + p], 0.f);
#pragma unroll
        for (int d = 0; d < 8; ++d) vv[d] = base[(16 + d) * PIX + p];
#pragma unroll
        for (int d = 0; d < 8; ++d)
#pragma unroll
            for (int e = 0; e < 8; ++e)
                acc[d][e] = fmaf(vv[d], kk[e], acc[d][e]);
#pragma unroll
        for (int e = 0; e < 8; ++e) acc[8][e] += kk[e];
    }

#pragma unroll
    for (int i = 0; i < 9; ++i)
#pragma unroll
        for (int j = 0; j < 8; ++j) {
            float s = acc[i][j];
            for (int off = 32; off; off >>= 1) s += __shfl_down(s, off, 64);
            acc[i][j] = s;
        }

    __shared__ float red[4][72];
    const int wave = threadIdx.x >> 6, lane = threadIdx.x & 63;
    if (lane == 0) {
#pragma unroll
        for (int i = 0; i < 9; ++i)
#pragma unroll
            for (int j = 0; j < 8; ++j) red[wave][i * 8 + j] = acc[i][j];
    }
    __syncthreads();
    const int t = threadIdx.x;
    if (t < 72) {
        float s = red[0][t] + red[1][t] + red[2][t] + red[3][t];
        vkout[((size_t)b * 96 + hh) * 72 + t] = s;
    }
}

// ---------------------------------------------------------------------------
// att_apply -> writes attT 2-way split bf16, [row=b*PIX+p][c=hh*8+d].
// ---------------------------------------------------------------------------
__global__ __launch_bounds__(256) void att_apply_kernel(
    const float* __restrict__ qkv, const float* __restrict__ s3,
    const float* __restrict__ s5, const float* __restrict__ vkin,
    unsigned short* __restrict__ aT, size_t stride)
{
    const int hh = blockIdx.y;
    const int b  = blockIdx.z;
    const int p  = blockIdx.x * 256 + threadIdx.x;

    __shared__ float vk[72];
    if (threadIdx.x < 72)
        vk[threadIdx.x] = vkin[((size_t)b * 96 + hh) * 72 + threadIdx.x];
    __syncthreads();

    const float* src = (hh < 32) ? qkv : ((hh < 64) ? s3 : s5);
    const int ch0 = (hh & 31) * 24;
    const float* base = src + ((size_t)b * C3 + ch0) * PIX + p;

    float q[8];
#pragma unroll
    for (int e = 0; e < 8; ++e) q[e] = fmaxf(base[(size_t)e * PIX], 0.f);

    float den = 0.f;
#pragma unroll
    for (int e = 0; e < 8; ++e) den = fmaf(vk[64 + e], q[e], den);
    const float inv = 1.f / (den + 1e-15f);

    union { unsigned short u[8]; uint4 v; } H, L;
#pragma unroll
    for (int d = 0; d < 8; ++d) {
        float num = 0.f;
#pragma unroll
        for (int e = 0; e < 8; ++e) num = fmaf(vk[d * 8 + e], q[e], num);
        float o = num * inv;
        unsigned short h = f2bf(o);
        H.u[d] = h;
        L.u[d] = f2bf(o - bf2f(h));
    }
    const size_t row = (size_t)b * PIX + p;
    *(uint4*)(aT + row * C3 + hh * 8) = H.v;
    *(uint4*)(aT + stride + row * C3 + hh * 8) = L.v;
}

// ---------------------------------------------------------------------------
extern "C" void kernel_launch(void* const* d_in, const int* in_sizes, int n_in,
                              void* d_out, int out_size, void* d_ws, size_t ws_size,
                              hipStream_t stream)
{
    const float* x      = (const float*)d_in[0];
    const float* qkv_w  = (const float*)d_in[1];
    const float* qkv_b  = (const float*)d_in[2];
    const float* dw3_w  = (const float*)d_in[3];
    const float* dw3_b  = (const float*)d_in[4];
    const float* pw3_w  = (const float*)d_in[5];
    const float* pw3_b  = (const float*)d_in[6];
    const float* dw5_w  = (const float*)d_in[7];
    const float* dw5_b  = (const float*)d_in[8];
    const float* pw5_w  = (const float*)d_in[9];
    const float* pw5_b  = (const float*)d_in[10];
    const float* proj_w = (const float*)d_in[11];
    const float* proj_b = (const float*)d_in[12];
    float* out = (float*)d_out;

    const size_t SZb = (size_t)C3 * PIX;       // 3,145,728 elems
    const size_t XTb = (size_t)256 * PIX;      // 1,048,576 elems
    const int    NW  = C3 * 256;               // 196,608 weight elems

    const size_t wbytes = (3 + 2) * (size_t)NW * 2;

    int cb = NB;
    while (cb > 1) {
        size_t need = wbytes +
                      (size_t)cb * (3 * SZb * 4 + 3 * XTb * 2 + 2 * SZb * 2 +
                                    (size_t)96 * 72 * 4);
        if (need <= ws_size) break;
        cb >>= 1;
    }

    char* wp = (char*)d_ws;
    unsigned short* WQ = (unsigned short*)wp;   wp += 3 * (size_t)NW * 2;
    unsigned short* WP = (unsigned short*)wp;   wp += 2 * (size_t)NW * 2;
    float* qkv = (float*)wp;                    wp += (size_t)cb * SZb * 4;
    float* t3  = (float*)wp;                    wp += (size_t)cb * SZb * 4;
    float* t5  = (float*)wp;                    wp += (size_t)cb * SZb * 4;
    unsigned short* xT = (unsigned short*)wp;   wp += 3 * (size_t)cb * XTb * 2;
    unsigned short* aT = (unsigned short*)wp;   wp += 2 * (size_t)cb * SZb * 2;
    float* vkb = (float*)wp;

    const size_t strideXT = (size_t)cb * XTb;
    const size_t strideAT = (size_t)cb * SZb;

    split3_kernel<<<(NW + 255) / 256, 256, 0, stream>>>(qkv_w, WQ, (size_t)NW, NW);
    split2_kernel<<<(NW + 255) / 256, 256, 0, stream>>>(proj_w, WP, (size_t)NW, NW);

    for (int b0 = 0; b0 < NB; b0 += cb) {
        const float* xb = x   + (size_t)b0 * 256 * PIX;
        float*       ob = out + (size_t)b0 * 256 * PIX;

        // 0. transpose-convert x -> xT 3-way split
        transpose_split3_kernel<<<dim3(128, 8, cb), 256, 0, stream>>>(xb, xT, strideXT);

        // 1. qkv GEMM (M=768, K=256), 3-way split: Mtiles = 768/128 = 6
        gemm_mfma_splitS<256, 3><<<dim3(6 * cb * 64), 256, 0, stream>>>(
            WQ, xT, qkv_b, qkv, 6, C3, (size_t)NW, strideXT);

        // 2+3. fused depthwise + grouped pointwise (register outer-product pw)
        dwpw_kernel<<<dim3(16, 32, cb), 256, 0, stream>>>(
            qkv, dw3_w, dw3_b, dw5_w, dw5_b,
            pw3_w, pw3_b, pw5_w, pw5_b, t3, t5);

        // 4. vk reduction
        vk_reduce_kernel<<<dim3(96, cb), 256, 0, stream>>>(qkv, t3, t5, vkb);

        // 5. attention apply -> attT 2-way split
        att_apply_kernel<<<dim3(16, 96, cb), 256, 0, stream>>>(
            qkv, t3, t5, vkb, aT, strideAT);

        // 6. proj GEMM (M=256, K=768), 2-way split: Mtiles = 256/128 = 2
        gemm_mfma_splitS<768, 2><<<dim3(2 * cb * 64), 256, 0, stream>>>(
            WP, aT, proj_b, ob, 2, 256, (size_t)NW, strideAT);
    }
}

// Round 9
// 536.377 us; speedup vs baseline: 1.0779x; 1.0779x over previous
//
#include <hip/hip_runtime.h>
#include <hip/hip_bf16.h>

#define C3 768
#define PIX 4096
#define NB 8

typedef __attribute__((ext_vector_type(8))) short bf16x8;
typedef __attribute__((ext_vector_type(4))) float f32x4;

__device__ __forceinline__ unsigned short f2bf(float f) {
    unsigned int u = __float_as_uint(f);
    u += 0x7fffu + ((u >> 16) & 1u);          // round-to-nearest-even
    return (unsigned short)(u >> 16);
}
__device__ __forceinline__ float bf2f(unsigned short h) {
    return __uint_as_float((unsigned int)h << 16);
}

// Direct global->LDS DMA, 16B per lane; LDS dest = wave-uniform base + lane*16.
__device__ __forceinline__ void gload_lds16(const void* g, void* l) {
    __builtin_amdgcn_global_load_lds(
        (const __attribute__((address_space(1))) void*)g,
        (__attribute__((address_space(3))) void*)l, 16, 0, 0);
}

// ---------------------------------------------------------------------------
// 3-way split of fp32 into bf16 s0+s1+s2 (residual ~2^-27).
// ---------------------------------------------------------------------------
__global__ __launch_bounds__(256) void split3_kernel(
    const float* __restrict__ src, unsigned short* __restrict__ d,
    size_t stride, int n)
{
    int i = blockIdx.x * 256 + threadIdx.x;
    if (i < n) {
        float f = src[i];
        unsigned short h0 = f2bf(f);  float r1 = f - bf2f(h0);
        unsigned short h1 = f2bf(r1); float r2 = r1 - bf2f(h1);
        d[i]              = h0;
        d[i + stride]     = h1;
        d[i + 2 * stride] = f2bf(r2);
    }
}

// 2-way split (residual ~2^-18) — for proj weights.
__global__ __launch_bounds__(256) void split2_kernel(
    const float* __restrict__ src, unsigned short* __restrict__ d,
    size_t stride, int n)
{
    int i = blockIdx.x * 256 + threadIdx.x;
    if (i < n) {
        float f = src[i];
        unsigned short h0 = f2bf(f);
        d[i]          = h0;
        d[i + stride] = f2bf(f - bf2f(h0));
    }
}

// ---------------------------------------------------------------------------
// Transpose-convert: x[b][k=256][p=4096] -> xT [3 splits][b*PIX+p][k] bf16.
// ---------------------------------------------------------------------------
__global__ __launch_bounds__(256) void transpose_split3_kernel(
    const float* __restrict__ src, unsigned short* __restrict__ d, size_t stride)
{
    __shared__ float t[32][33];
    const int b  = blockIdx.z;
    const int p0 = blockIdx.x * 32;
    const int k0 = blockIdx.y * 32;
    const int tx = threadIdx.x & 31, ty = threadIdx.x >> 5;   // 32 x 8

    const float* s = src + ((size_t)b * 256 + k0) * PIX + p0;
#pragma unroll
    for (int i = 0; i < 4; ++i)
        t[ty + i * 8][tx] = s[(size_t)(ty + i * 8) * PIX + tx];   // t[k][p]
    __syncthreads();
#pragma unroll
    for (int i = 0; i < 4; ++i) {
        const int p = ty + i * 8;
        float f = t[tx][p];                   // (k=k0+tx, p=p0+p)
        unsigned short h0 = f2bf(f);  float r1 = f - bf2f(h0);
        unsigned short h1 = f2bf(r1); float r2 = r1 - bf2f(h1);
        size_t o = ((size_t)b * PIX + p0 + p) * 256 + k0 + tx;
        d[o]              = h0;
        d[o + stride]     = h1;
        d[o + 2 * stride] = f2bf(r2);
    }
}

// ---------------------------------------------------------------------------
// Split-bf16 MFMA GEMM, S splits, products with i+j < S.
//   Y[b,m,p] = sum_k W[m,k] * B[(b,p)][k] + bias[m]
// BM=128, BN=64, BK=64. 4 waves, each 64x32 (4x2 mfma_16x16x32 subtiles).
// Staging via global_load_lds; swizzle via pre-swizzled global source.
// XCD-chunked blockIdx swizzle for per-XCD L2 reuse.
// ---------------------------------------------------------------------------
template <int K, int S>
__global__ __launch_bounds__(256) void gemm_mfma_splitS(
    const unsigned short* __restrict__ A, const unsigned short* __restrict__ Bm,
    const float* __restrict__ bias, float* __restrict__ Y,
    int Mtiles, int M, size_t strideA, size_t strideB)
{
    __shared__ char lds[S * 24576];
    char* sA[S];
    char* sB[S];
#pragma unroll
    for (int s = 0; s < S; ++s) {
        sA[s] = lds + s * 16384;                 // 128 rows x 128B
        sB[s] = lds + S * 16384 + s * 8192;      // 64 rows x 128B
    }

    // XCD-chunked swizzle (gridDim.x is always a multiple of 8 here)
    const int nwg = gridDim.x;
    const int per = nwg >> 3;
    const int bid = blockIdx.x;
    const int wg  = (bid & 7) * per + (bid >> 3);
    const int tm  = wg % Mtiles;
    const int tn  = wg / Mtiles;
    const int bm  = tm * 128;
    const int gn0 = tn * 64;                     // global B-row = b*4096+p

    const int tid  = threadIdx.x;
    const int lane = tid & 63;
    const int wv   = tid >> 6;
    const int m0w  = (wv & 1) * 64;
    const int n0w  = (wv >> 1) * 32;

    // staging: wave wv deposits 1024B = 8 rows x 128B; lane l -> row rowbase+(l>>3),
    // global chunk = (l&7)*16 ^ ((l>>3)<<4)  (row&7 == l>>3).
    const int l8  = lane >> 3;
    const int c16 = (lane & 7) * 16;
    const int gchunk = (c16 ^ (l8 << 4)) >> 1;          // elements
    const unsigned short* gA = A  + (size_t)(bm  + wv * 8 + l8) * K + gchunk;
    const unsigned short* gB = Bm + (size_t)(gn0 + wv * 8 + l8) * K + gchunk;
    const int ldsw = wv * 1024;

    f32x4 acc[4][2] = {};

    for (int k0 = 0; k0 < K; k0 += 64) {
        __syncthreads();                 // previous compute done before overwrite
#pragma unroll
        for (int s = 0; s < S; ++s) {
#pragma unroll
            for (int j = 0; j < 4; ++j)  // A: 128 rows = 4 calls x (4 waves x 8 rows)
                gload_lds16(gA + s * strideA + (size_t)j * 32 * K + k0,
                            sA[s] + ldsw + j * 4096);
#pragma unroll
            for (int j = 0; j < 2; ++j)  // B: 64 rows
                gload_lds16(gB + s * strideB + (size_t)j * 32 * K + k0,
                            sB[s] + ldsw + j * 4096);
        }
        __syncthreads();                 // compiler drains vmcnt(0) before barrier

#pragma unroll
        for (int kk = 0; kk < 2; ++kk) {
            const int kbyte = (kk * 32 + (lane >> 4) * 8) * 2;
            bf16x8 bfr[S][2];
#pragma unroll
            for (int ni = 0; ni < 2; ++ni) {
                const int r = n0w + ni * 16 + (lane & 15);
                const int byte = r * 128 + (kbyte ^ ((r & 7) << 4));
#pragma unroll
                for (int s = 0; s < S; ++s)
                    bfr[s][ni] = *(const bf16x8*)(sB[s] + byte);
            }
#pragma unroll
            for (int mi = 0; mi < 4; ++mi) {
                bf16x8 afr[S];
                const int r = m0w + mi * 16 + (lane & 15);
                const int byte = r * 128 + (kbyte ^ ((r & 7) << 4));
#pragma unroll
                for (int s = 0; s < S; ++s)
                    afr[s] = *(const bf16x8*)(sA[s] + byte);
#pragma unroll
                for (int ni = 0; ni < 2; ++ni) {
#pragma unroll
                    for (int i = 0; i < S; ++i)
#pragma unroll
                        for (int j = 0; j < S; ++j)
                            if (i + j < S)
                                acc[mi][ni] = __builtin_amdgcn_mfma_f32_16x16x32_bf16(
                                    afr[i], bfr[j][ni], acc[mi][ni], 0, 0, 0);
                }
            }
        }
    }

    const int b  = gn0 >> 12;
    const int p0 = gn0 & 4095;
#pragma unroll
    for (int mi = 0; mi < 4; ++mi)
#pragma unroll
        for (int ni = 0; ni < 2; ++ni) {
            const int p = p0 + n0w + ni * 16 + (lane & 15);
#pragma unroll
            for (int i = 0; i < 4; ++i) {
                const int m = bm + m0w + mi * 16 + (lane >> 4) * 4 + i;
                Y[((size_t)b * M + m) * PIX + p] = acc[mi][ni][i] + bias[m];
            }
        }
}

// ---------------------------------------------------------------------------
// Fused depthwise(3x3 & 5x5) + grouped pointwise (24->24), one group/block.
// v3: register outer-product pw (48 accumulators) with __launch_bounds__(256,4)
// to pin the VGPR budget at 128 (v2's default allocation spilled them to
// scratch: VGPR_Count=40 < 48 accumulators -> VALUBusy 19%). Static-index
// staging (no int division).
// ---------------------------------------------------------------------------
__global__ __launch_bounds__(256, 4) void dwpw_kernel(
    const float* __restrict__ qkv,
    const float* __restrict__ w3,  const float* __restrict__ b3,
    const float* __restrict__ w5,  const float* __restrict__ b5,
    const float* __restrict__ pw3w, const float* __restrict__ pw3b,
    const float* __restrict__ pw5w, const float* __restrict__ pw5b,
    float* __restrict__ t3, float* __restrict__ t5)
{
    __shared__ float tile[2][8][68];        // 4352 B total

    const int g   = blockIdx.y;
    const int b   = blockIdx.z;
    const int tid = threadIdx.x;
    const int p   = blockIdx.x * 256 + tid; // output pixel
    const int r0  = blockIdx.x * 4;         // first output row of this block
    const int c0  = g * 24;
    const int lr  = tid >> 6;               // local row 0..3
    const int lc  = tid & 63;               // col 0..63

    const float* src0 = qkv + ((size_t)b * C3 + c0) * PIX;

    // register accumulators for the grouped pointwise (outer-product form)
    float o3[24], o5[24];
#pragma unroll
    for (int co = 0; co < 24; ++co) {
        o3[co] = pw3b[c0 + co];
        o5[co] = pw5b[c0 + co];
    }

    // stage channel ic into buffer buf (zero-padded 8x68 halo tile),
    // static indexing only
    auto stage = [&](int ic, int buf) {
        const float* src = src0 + (size_t)ic * PIX;
#pragma unroll
        for (int j = 0; j < 2; ++j) {
            const int rr = (tid >> 6) + j * 4;
            const int cc = tid & 63;
            const int gr = r0 - 2 + rr, gc = cc - 2;
            float v = 0.f;
            if ((unsigned)gr < 64u && (unsigned)gc < 64u) v = src[gr * 64 + gc];
            tile[buf][rr][cc] = v;
        }
        if (tid < 32) {                     // cols 64..67, all 8 rows
            const int rr = tid >> 2;
            const int cc = 64 + (tid & 3);
            const int gr = r0 - 2 + rr, gc = cc - 2;
            float v = 0.f;
            if ((unsigned)gr < 64u && (unsigned)gc < 64u) v = src[gr * 64 + gc];
            tile[buf][rr][cc] = v;
        }
    };

    stage(0, 0);
    for (int ic = 0; ic < 24; ++ic) {
        __syncthreads();                    // stage(ic) visible; compute(ic-1) done
        if (ic + 1 < 24) stage(ic + 1, (ic + 1) & 1);

        const int c = c0 + ic;
        const float* k5 = w5 + c * 25;
        const float* k3 = w3 + c * 9;
        const float (*T)[68] = tile[ic & 1];

        float acc3 = b3[c], acc5 = b5[c];
#pragma unroll
        for (int dy = 0; dy < 5; ++dy) {
#pragma unroll
            for (int dx = 0; dx < 5; ++dx) {
                const float v = T[lr + dy][lc + dx];
                acc5 = fmaf(k5[dy * 5 + dx], v, acc5);
                if (dy >= 1 && dy <= 3 && dx >= 1 && dx <= 3)
                    acc3 = fmaf(k3[(dy - 1) * 3 + (dx - 1)], v, acc3);
            }
        }

        const float* w3g = pw3w + (size_t)c0 * 24 + ic;   // pw3w[(c0+co)*24+ic]
        const float* w5g = pw5w + (size_t)c0 * 24 + ic;
#pragma unroll
        for (int co = 0; co < 24; ++co) {
            o3[co] = fmaf(w3g[co * 24], acc3, o3[co]);
            o5[co] = fmaf(w5g[co * 24], acc5, o5[co]);
        }
    }

    float* dst3 = t3 + ((size_t)b * C3 + c0) * PIX + p;
    float* dst5 = t5 + ((size_t)b * C3 + c0) * PIX + p;
#pragma unroll
    for (int co = 0; co < 24; ++co) {
        dst3[(size_t)co * PIX] = o3[co];
        dst5[(size_t)co * PIX] = o5[co];
    }
}

// ---------------------------------------------------------------------------
// vk[b,hh][d(9)][e(8)] = sum_p v_aug[d,p] * relu(k[e,p])
// ---------------------------------------------------------------------------
__global__ __launch_bounds__(256) void vk_reduce_kernel(
    const float* __restrict__ qkv, const float* __restrict__ s3,
    const float* __restrict__ s5, float* __restrict__ vkout)
{
    const int hh = blockIdx.x;  // 0..95
    const int b  = blockIdx.y;
    const float* src = (hh < 32) ? qkv : ((hh < 64) ? s3 : s5);
    const int ch0 = (hh & 31) * 24;
    const float* base = src + ((size_t)b * C3 + ch0) * PIX;

    float acc[9][8] = {};
    for (int p = threadIdx.x; p < PIX; p += 256) {
        float kk[8], vv[8];
#pragma unroll
        for (int e = 0; e < 8; ++e) kk[e] = fmaxf(base[(8 + e) * PIX + p], 0.f);
#pragma unroll
        for (int d = 0; d < 8; ++d) vv[d] = base[(16 + d) * PIX + p];
#pragma unroll
        for (int d = 0; d < 8; ++d)
#pragma unroll
            for (int e = 0; e < 8; ++e)
                acc[d][e] = fmaf(vv[d], kk[e], acc[d][e]);
#pragma unroll
        for (int e = 0; e < 8; ++e) acc[8][e] += kk[e];
    }

#pragma unroll
    for (int i = 0; i < 9; ++i)
#pragma unroll
        for (int j = 0; j < 8; ++j) {
            float s = acc[i][j];
            for (int off = 32; off; off >>= 1) s += __shfl_down(s, off, 64);
            acc[i][j] = s;
        }

    __shared__ float red[4][72];
    const int wave = threadIdx.x >> 6, lane = threadIdx.x & 63;
    if (lane == 0) {
#pragma unroll
        for (int i = 0; i < 9; ++i)
#pragma unroll
            for (int j = 0; j < 8; ++j) red[wave][i * 8 + j] = acc[i][j];
    }
    __syncthreads();
    const int t = threadIdx.x;
    if (t < 72) {
        float s = red[0][t] + red[1][t] + red[2][t] + red[3][t];
        vkout[((size_t)b * 96 + hh) * 72 + t] = s;
    }
}

// ---------------------------------------------------------------------------
// att_apply -> writes attT 2-way split bf16, [row=b*PIX+p][c=hh*8+d].
// ---------------------------------------------------------------------------
__global__ __launch_bounds__(256) void att_apply_kernel(
    const float* __restrict__ qkv, const float* __restrict__ s3,
    const float* __restrict__ s5, const float* __restrict__ vkin,
    unsigned short* __restrict__ aT, size_t stride)
{
    const int hh = blockIdx.y;
    const int b  = blockIdx.z;
    const int p  = blockIdx.x * 256 + threadIdx.x;

    __shared__ float vk[72];
    if (threadIdx.x < 72)
        vk[threadIdx.x] = vkin[((size_t)b * 96 + hh) * 72 + threadIdx.x];
    __syncthreads();

    const float* src = (hh < 32) ? qkv : ((hh < 64) ? s3 : s5);
    const int ch0 = (hh & 31) * 24;
    const float* base = src + ((size_t)b * C3 + ch0) * PIX + p;

    float q[8];
#pragma unroll
    for (int e = 0; e < 8; ++e) q[e] = fmaxf(base[(size_t)e * PIX], 0.f);

    float den = 0.f;
#pragma unroll
    for (int e = 0; e < 8; ++e) den = fmaf(vk[64 + e], q[e], den);
    const float inv = 1.f / (den + 1e-15f);

    union { unsigned short u[8]; uint4 v; } H, L;
#pragma unroll
    for (int d = 0; d < 8; ++d) {
        float num = 0.f;
#pragma unroll
        for (int e = 0; e < 8; ++e) num = fmaf(vk[d * 8 + e], q[e], num);
        float o = num * inv;
        unsigned short h = f2bf(o);
        H.u[d] = h;
        L.u[d] = f2bf(o - bf2f(h));
    }
    const size_t row = (size_t)b * PIX + p;
    *(uint4*)(aT + row * C3 + hh * 8) = H.v;
    *(uint4*)(aT + stride + row * C3 + hh * 8) = L.v;
}

// ---------------------------------------------------------------------------
extern "C" void kernel_launch(void* const* d_in, const int* in_sizes, int n_in,
                              void* d_out, int out_size, void* d_ws, size_t ws_size,
                              hipStream_t stream)
{
    const float* x      = (const float*)d_in[0];
    const float* qkv_w  = (const float*)d_in[1];
    const float* qkv_b  = (const float*)d_in[2];
    const float* dw3_w  = (const float*)d_in[3];
    const float* dw3_b  = (const float*)d_in[4];
    const float* pw3_w  = (const float*)d_in[5];
    const float* pw3_b  = (const float*)d_in[6];
    const float* dw5_w  = (const float*)d_in[7];
    const float* dw5_b  = (const float*)d_in[8];
    const float* pw5_w  = (const float*)d_in[9];
    const float* pw5_b  = (const float*)d_in[10];
    const float* proj_w = (const float*)d_in[11];
    const float* proj_b = (const float*)d_in[12];
    float* out = (float*)d_out;

    const size_t SZb = (size_t)C3 * PIX;       // 3,145,728 elems
    const size_t XTb = (size_t)256 * PIX;      // 1,048,576 elems
    const int    NW  = C3 * 256;               // 196,608 weight elems

    const size_t wbytes = (3 + 2) * (size_t)NW * 2;

    int cb = NB;
    while (cb > 1) {
        size_t need = wbytes +
                      (size_t)cb * (3 * SZb * 4 + 3 * XTb * 2 + 2 * SZb * 2 +
                                    (size_t)96 * 72 * 4);
        if (need <= ws_size) break;
        cb >>= 1;
    }

    char* wp = (char*)d_ws;
    unsigned short* WQ = (unsigned short*)wp;   wp += 3 * (size_t)NW * 2;
    unsigned short* WP = (unsigned short*)wp;   wp += 2 * (size_t)NW * 2;
    float* qkv = (float*)wp;                    wp += (size_t)cb * SZb * 4;
    float* t3  = (float*)wp;                    wp += (size_t)cb * SZb * 4;
    float* t5  = (float*)wp;                    wp += (size_t)cb * SZb * 4;
    unsigned short* xT = (unsigned short*)wp;   wp += 3 * (size_t)cb * XTb * 2;
    unsigned short* aT = (unsigned short*)wp;   wp += 2 * (size_t)cb * SZb * 2;
    float* vkb = (float*)wp;

    const size_t strideXT = (size_t)cb * XTb;
    const size_t strideAT = (size_t)cb * SZb;

    split3_kernel<<<(NW + 255) / 256, 256, 0, stream>>>(qkv_w, WQ, (size_t)NW, NW);
    split2_kernel<<<(NW + 255) / 256, 256, 0, stream>>>(proj_w, WP, (size_t)NW, NW);

    for (int b0 = 0; b0 < NB; b0 += cb) {
        const float* xb = x   + (size_t)b0 * 256 * PIX;
        float*       ob = out + (size_t)b0 * 256 * PIX;

        // 0. transpose-convert x -> xT 3-way split
        transpose_split3_kernel<<<dim3(128, 8, cb), 256, 0, stream>>>(xb, xT, strideXT);

        // 1. qkv GEMM (M=768, K=256), 3-way split: Mtiles = 768/128 = 6
        gemm_mfma_splitS<256, 3><<<dim3(6 * cb * 64), 256, 0, stream>>>(
            WQ, xT, qkv_b, qkv, 6, C3, (size_t)NW, strideXT);

        // 2+3. fused depthwise + grouped pointwise (register outer-product pw)
        dwpw_kernel<<<dim3(16, 32, cb), 256, 0, stream>>>(
            qkv, dw3_w, dw3_b, dw5_w, dw5_b,
            pw3_w, pw3_b, pw5_w, pw5_b, t3, t5);

        // 4. vk reduction
        vk_reduce_kernel<<<dim3(96, cb), 256, 0, stream>>>(qkv, t3, t5, vkb);

        // 5. attention apply -> attT 2-way split
        att_apply_kernel<<<dim3(16, 96, cb), 256, 0, stream>>>(
            qkv, t3, t5, vkb, aT, strideAT);

        // 6. proj GEMM (M=256, K=768), 2-way split: Mtiles = 256/128 = 2
        gemm_mfma_splitS<768, 2><<<dim3(2 * cb * 64), 256, 0, stream>>>(
            WP, aT, proj_b, ob, 2, 256, (size_t)NW, strideAT);
    }
}